// Round 1
// baseline (1315.979 us; speedup 1.0000x reference)
//
#include <hip/hip_runtime.h>
#include <hip/hip_bf16.h>

// ---------------------------------------------------------------------------
// BotGraphSAGE: fused front MLP -> 2x (SAGEConv 128->64->128) -> output head.
// Strategy:
//  - All aggregations reduced to 64-d by projecting before segment-mean
//    (linearity of segment_sum).
//  - CSR built per launch (hist -> scan -> scatter), reused for 4 aggs.
//  - fp32 vector-ALU GEMMs (no fp32 MFMA on CDNA4), LDS-staged X tiles,
//    4 nodes x 8 outs per thread register tile.
// ---------------------------------------------------------------------------

__global__ void hist_kernel(const int* __restrict__ dst, int* __restrict__ cnt, int E) {
    int e = blockIdx.x * 256 + threadIdx.x;
    if (e < E) atomicAdd(&cnt[dst[e]], 1);
}

__global__ void scan_kernel(const int* __restrict__ cnt, int* __restrict__ off,
                            int* __restrict__ cursor, float* __restrict__ invc, int n) {
    __shared__ int sd[1024];
    __shared__ int carry;
    int tid = threadIdx.x;
    if (tid == 0) { carry = 0; off[0] = 0; }
    __syncthreads();
    for (int base = 0; base < n; base += 1024) {
        int v = (base + tid < n) ? cnt[base + tid] : 0;
        sd[tid] = v;
        __syncthreads();
        for (int d = 1; d < 1024; d <<= 1) {
            int t2 = (tid >= d) ? sd[tid - d] : 0;
            __syncthreads();
            sd[tid] += t2;
            __syncthreads();
        }
        if (base + tid < n) {
            int inc = carry + sd[tid];
            off[base + tid + 1] = inc;
            cursor[base + tid] = inc - v;
            invc[base + tid] = 1.0f / fmaxf((float)v, 1.0f);
        }
        __syncthreads();
        if (tid == 0) carry += sd[1023];
        __syncthreads();
    }
}

__global__ void scatter_kernel(const int* __restrict__ src, const int* __restrict__ dst,
                               int* __restrict__ cursor, int* __restrict__ csr, int E) {
    int e = blockIdx.x * 256 + threadIdx.x;
    if (e < E) {
        int d = dst[e];
        int p = atomicAdd(&cursor[d], 1);
        csr[p] = src[e];
    }
}

// des[N,768] @ W_des[768,32] + b -> leaky -> Xout[:,0:32] (stride 128)
__global__ __launch_bounds__(256) void f1a_kernel(const float* __restrict__ des,
    const float* __restrict__ W, const float* __restrict__ b,
    float* __restrict__ Xout, int n)
{
    __shared__ float sX[64 * 132];
    int t = threadIdx.x;
    int tx = t & 7, ty = t >> 3;      // tx: 8 output groups of 4; ty: 32 node groups of 2
    int nbase = blockIdx.x * 64;
    float acc[2][4];
#pragma unroll
    for (int j = 0; j < 2; ++j)
#pragma unroll
        for (int i = 0; i < 4; ++i) acc[j][i] = 0.f;

    for (int kb = 0; kb < 768; kb += 128) {
        __syncthreads();
        for (int i = t; i < 64 * 128; i += 256) {
            int nn = i >> 7, k = i & 127;
            int gn = nbase + nn;
            sX[nn * 132 + k] = (gn < n) ? des[(size_t)gn * 768 + kb + k] : 0.f;
        }
        __syncthreads();
        const float* wp = W + (size_t)kb * 32 + tx * 4;
#pragma unroll 4
        for (int k2 = 0; k2 < 128; ++k2) {
            float4 w = *reinterpret_cast<const float4*>(wp);
            wp += 32;
            float x0 = sX[(ty * 2 + 0) * 132 + k2];
            float x1 = sX[(ty * 2 + 1) * 132 + k2];
            acc[0][0] += x0 * w.x; acc[0][1] += x0 * w.y; acc[0][2] += x0 * w.z; acc[0][3] += x0 * w.w;
            acc[1][0] += x1 * w.x; acc[1][1] += x1 * w.y; acc[1][2] += x1 * w.z; acc[1][3] += x1 * w.w;
        }
    }
#pragma unroll
    for (int j = 0; j < 2; ++j) {
        int gn = nbase + ty * 2 + j;
        if (gn >= n) continue;
#pragma unroll
        for (int i = 0; i < 4; ++i) {
            int o = tx * 4 + i;
            float v = acc[j][i] + b[o];
            v = v > 0.f ? v : 0.01f * v;
            Xout[(size_t)gn * 128 + o] = v;
        }
    }
}

// num/cat small linears -> leaky -> Xout[:,32:116]
__global__ __launch_bounds__(256) void f1b_kernel(const float* __restrict__ nump,
    const float* __restrict__ catp,
    const float* __restrict__ Wn, const float* __restrict__ bn,
    const float* __restrict__ Wc, const float* __restrict__ bc,
    float* __restrict__ Xout, int n)
{
    int idx = blockIdx.x * 256 + threadIdx.x;
    if (idx >= n * 84) return;
    int node = idx / 84;
    int c = idx - node * 84;
    float v;
    if (c < 42) {
        v = bn[c];
#pragma unroll
        for (int k = 0; k < 4; ++k) v += nump[node * 4 + k] * Wn[k * 42 + c];
    } else {
        int o = c - 42;
        v = bc[o];
#pragma unroll
        for (int k = 0; k < 3; ++k) v += catp[node * 3 + k] * Wc[k * 42 + o];
    }
    v = v > 0.f ? v : 0.01f * v;
    Xout[(size_t)node * 128 + 32 + c] = v;
}

// Generic [N,K] @ [K,128] GEMM, X stride ldx, output stride 128.
// MODE 0: W = WA[K][128]
// MODE 1: cols 0:64 from WA[K][64], cols 64:128 from WB[K][64]  (col-concat)
// MODE 2: rows 0:64 from WA[64][128], rows 64:128 from WB[64][128] (row-concat)
// BIASM 0: none; 1: bias[128]; 2: bias[64] applied to cols >= 64
// ACT 0: none; 1: relu; 2: leaky(0.01)
template<int K, int MODE, int ACT, int BIASM>
__global__ __launch_bounds__(256) void gemm128_kernel(
    const float* __restrict__ X, int ldx,
    const float* __restrict__ WA, const float* __restrict__ WB,
    const float* __restrict__ bias,
    float* __restrict__ Y, int n)
{
    __shared__ float sX[64 * 132];
    int t = threadIdx.x;
    int tx = t & 15, ty = t >> 4;     // tx: 16 output groups of 8; ty: 16 node groups of 4
    int nbase = blockIdx.x * 64;
    for (int i = t; i < 64 * 128; i += 256) {
        int nn = i >> 7, k = i & 127;
        float v = 0.f;
        int gn = nbase + nn;
        if (k < K && gn < n) v = X[(size_t)gn * ldx + k];
        sX[nn * 132 + k] = v;
    }
    __syncthreads();

    float acc[4][8];
#pragma unroll
    for (int j = 0; j < 4; ++j)
#pragma unroll
        for (int i = 0; i < 8; ++i) acc[j][i] = 0.f;

    const float* wp;
    int wstride;
    if (MODE == 1) { wp = (tx < 8) ? (WA + tx * 8) : (WB + tx * 8 - 64); wstride = 64; }
    else { wp = WA + tx * 8; wstride = 128; }

#pragma unroll 4
    for (int k = 0; k < K; ++k) {
        if (MODE == 2 && k == 64) wp = WB + tx * 8;
        float4 w0 = *reinterpret_cast<const float4*>(wp);
        float4 w1 = *reinterpret_cast<const float4*>(wp + 4);
        wp += wstride;
        float xv[4];
#pragma unroll
        for (int j = 0; j < 4; ++j) xv[j] = sX[(ty * 4 + j) * 132 + k];
#pragma unroll
        for (int j = 0; j < 4; ++j) {
            acc[j][0] += xv[j] * w0.x; acc[j][1] += xv[j] * w0.y;
            acc[j][2] += xv[j] * w0.z; acc[j][3] += xv[j] * w0.w;
            acc[j][4] += xv[j] * w1.x; acc[j][5] += xv[j] * w1.y;
            acc[j][6] += xv[j] * w1.z; acc[j][7] += xv[j] * w1.w;
        }
    }
#pragma unroll
    for (int j = 0; j < 4; ++j) {
        int gn = nbase + ty * 4 + j;
        if (gn >= n) continue;
#pragma unroll
        for (int i = 0; i < 8; ++i) {
            int o = tx * 8 + i;
            float v = acc[j][i];
            if (BIASM == 1) v += bias[o];
            if (BIASM == 2) { if (o >= 64) v += bias[o - 64]; }
            if (ACT == 1) v = fmaxf(v, 0.f);
            else if (ACT == 2) v = v > 0.f ? v : 0.01f * v;
            Y[(size_t)gn * 128 + o] = v;
        }
    }
}

// SAGE layer-a epilogue: H[dst] = relu(mean_agg(Y[:,0:64]) + Y[dst,64:128])
// (bl already folded into Y cols 64:128 by the GEMM). One wave per dst node.
__global__ __launch_bounds__(256) void agg_a_kernel(const float* __restrict__ Y,
    const int* __restrict__ off, const int* __restrict__ csr,
    const float* __restrict__ invc, float* __restrict__ H, int n)
{
    int wid = (blockIdx.x * 256 + threadIdx.x) >> 6;
    int f = threadIdx.x & 63;
    if (wid >= n) return;
    int b = off[wid], e = off[wid + 1];
    float acc = 0.f;
    for (; b + 4 <= e; b += 4) {
        int s0 = csr[b], s1 = csr[b + 1], s2 = csr[b + 2], s3 = csr[b + 3];
        float v0 = Y[(size_t)s0 * 128 + f];
        float v1 = Y[(size_t)s1 * 128 + f];
        float v2 = Y[(size_t)s2 * 128 + f];
        float v3 = Y[(size_t)s3 * 128 + f];
        acc += v0 + v1 + v2 + v3;
    }
    for (; b < e; ++b) acc += Y[(size_t)csr[b] * 128 + f];
    float v = acc * invc[wid] + Y[(size_t)wid * 128 + 64 + f];
    H[(size_t)wid * 64 + f] = fmaxf(v, 0.f);
}

// SAGE layer-b pre-GEMM: Z[dst,0:64] = mean_agg(H), Z[dst,64:128] = H[dst]
__global__ __launch_bounds__(256) void agg_b_kernel(const float* __restrict__ H,
    const int* __restrict__ off, const int* __restrict__ csr,
    const float* __restrict__ invc, float* __restrict__ Z, int n)
{
    int wid = (blockIdx.x * 256 + threadIdx.x) >> 6;
    int f = threadIdx.x & 63;
    if (wid >= n) return;
    int b = off[wid], e = off[wid + 1];
    float acc = 0.f;
    for (; b + 4 <= e; b += 4) {
        int s0 = csr[b], s1 = csr[b + 1], s2 = csr[b + 2], s3 = csr[b + 3];
        acc += H[(size_t)s0 * 64 + f] + H[(size_t)s1 * 64 + f]
             + H[(size_t)s2 * 64 + f] + H[(size_t)s3 * 64 + f];
    }
    for (; b < e; ++b) acc += H[(size_t)csr[b] * 64 + f];
    Z[(size_t)wid * 128 + f] = acc * invc[wid];
    Z[(size_t)wid * 128 + 64 + f] = H[(size_t)wid * 64 + f];
}

// Head: out = (leaky(X @ W1 + b1)) @ W2 + b2, 8 nodes/block.
__global__ __launch_bounds__(256) void f3_kernel(const float* __restrict__ X,
    const float* __restrict__ W1, const float* __restrict__ b1,
    const float* __restrict__ W2, const float* __restrict__ b2,
    float* __restrict__ out, int n)
{
    __shared__ float sX[8 * 132];
    __shared__ float sRed[4][4][2];
    int t = threadIdx.x;
    int nbase = blockIdx.x * 8;
    for (int i = t; i < 8 * 128; i += 256) {
        int nn = i >> 7, k = i & 127;
        int gn = nbase + nn;
        sX[nn * 132 + k] = (gn < n) ? X[(size_t)gn * 128 + k] : 0.f;
    }
    __syncthreads();
    int o = t & 127, g = t >> 7;
    float acc[4] = {0.f, 0.f, 0.f, 0.f};
#pragma unroll 4
    for (int k = 0; k < 128; ++k) {
        float w = W1[k * 128 + o];
#pragma unroll
        for (int j = 0; j < 4; ++j) acc[j] += sX[(g * 4 + j) * 132 + k] * w;
    }
    float w20 = W2[o * 2 + 0], w21 = W2[o * 2 + 1];
    float p[4][2];
#pragma unroll
    for (int j = 0; j < 4; ++j) {
        float v = acc[j] + b1[o];
        v = v > 0.f ? v : 0.01f * v;
        p[j][0] = v * w20; p[j][1] = v * w21;
    }
#pragma unroll
    for (int j = 0; j < 4; ++j) {
#pragma unroll
        for (int jj = 0; jj < 2; ++jj) {
            float v = p[j][jj];
            for (int s = 32; s > 0; s >>= 1) v += __shfl_down(v, s, 64);
            if ((t & 63) == 0) sRed[t >> 6][j][jj] = v;
        }
    }
    __syncthreads();
    if (t < 16) {
        int n2 = t >> 1, jj = t & 1;
        int g2 = n2 >> 2, j = n2 & 3;
        float v = sRed[g2 * 2 + 0][j][jj] + sRed[g2 * 2 + 1][j][jj] + b2[jj];
        int gn = nbase + n2;
        if (gn < n) out[(size_t)gn * 2 + jj] = v;
    }
}

extern "C" void kernel_launch(void* const* d_in, const int* in_sizes, int n_in,
                              void* d_out, int out_size, void* d_ws, size_t ws_size,
                              hipStream_t stream)
{
    const float* des   = (const float*)d_in[0];
    // d_in[1] = tweet (unused, per reference)
    const float* nump  = (const float*)d_in[2];
    const float* catp  = (const float*)d_in[3];
    const int*   ei    = (const int*)d_in[4];
    const float* W_des = (const float*)d_in[5];  const float* b_des = (const float*)d_in[6];
    const float* W_num = (const float*)d_in[7];  const float* b_num = (const float*)d_in[8];
    const float* W_cat = (const float*)d_in[9];  const float* b_cat = (const float*)d_in[10];
    const float* W_in  = (const float*)d_in[11]; const float* b_in  = (const float*)d_in[12];
    const float* s1a_Wl = (const float*)d_in[13]; const float* s1a_bl = (const float*)d_in[14];
    const float* s1a_Wr = (const float*)d_in[15];
    const float* s1b_Wl = (const float*)d_in[16]; const float* s1b_bl = (const float*)d_in[17];
    const float* s1b_Wr = (const float*)d_in[18];
    const float* s2a_Wl = (const float*)d_in[19]; const float* s2a_bl = (const float*)d_in[20];
    const float* s2a_Wr = (const float*)d_in[21];
    const float* s2b_Wl = (const float*)d_in[22]; const float* s2b_bl = (const float*)d_in[23];
    const float* s2b_Wr = (const float*)d_in[24];
    const float* W_o1  = (const float*)d_in[25]; const float* b_o1 = (const float*)d_in[26];
    const float* W_o2  = (const float*)d_in[27]; const float* b_o2 = (const float*)d_in[28];
    float* out = (float*)d_out;

    int N = in_sizes[0] / 768;
    int E = in_sizes[4] / 2;
    const int* srcp = ei;
    const int* dstp = ei + E;

    float* P0 = (float*)d_ws;
    float* P1 = P0 + (size_t)128 * N;
    float* P2 = P1 + (size_t)128 * N;
    int* cnt = (int*)(P2 + (size_t)128 * N);
    int* off = cnt + N;
    int* cursor = off + (N + 1);
    float* invc = (float*)(cursor + N);
    int* csr = (int*)(invc + N);

    // --- CSR build (reused by all 4 aggregations) ---
    hipMemsetAsync(cnt, 0, (size_t)N * sizeof(int), stream);
    int eb = (E + 255) / 256;
    hist_kernel<<<eb, 256, 0, stream>>>(dstp, cnt, E);
    scan_kernel<<<1, 1024, 0, stream>>>(cnt, off, cursor, invc, N);
    scatter_kernel<<<eb, 256, 0, stream>>>(srcp, dstp, cursor, csr, E);

    int nb64 = (N + 63) / 64;
    int nbw  = (N + 3) / 4;

    // --- Front MLP: x116 -> P0 (stride 128), x0 = leaky(x116 @ W_in + b_in) -> P1 ---
    f1a_kernel<<<nb64, 256, 0, stream>>>(des, W_des, b_des, P0, N);
    int nb_f1b = (N * 84 + 255) / 256;
    f1b_kernel<<<nb_f1b, 256, 0, stream>>>(nump, catp, W_num, b_num, W_cat, b_cat, P0, N);
    gemm128_kernel<116, 0, 2, 1><<<nb64, 256, 0, stream>>>(P0, 128, W_in, nullptr, b_in, P1, N);

    // --- SAGE block 1 ---
    // y = [x0@Wl | x0@Wr + bl] -> P0
    gemm128_kernel<128, 1, 0, 2><<<nb64, 256, 0, stream>>>(P1, 128, s1a_Wl, s1a_Wr, s1a_bl, P0, N);
    // h = relu(mean_agg(yl) + yr) -> P2
    agg_a_kernel<<<nbw, 256, 0, stream>>>(P0, off, csr, invc, P2, N);
    // z = [mean_agg(h) | h] -> P1 ; x1 = relu(z @ [Wl;Wr] + bl) -> P0
    agg_b_kernel<<<nbw, 256, 0, stream>>>(P2, off, csr, invc, P1, N);
    gemm128_kernel<128, 2, 1, 1><<<nb64, 256, 0, stream>>>(P1, 128, s1b_Wl, s1b_Wr, s1b_bl, P0, N);

    // --- SAGE block 2 ---
    gemm128_kernel<128, 1, 0, 2><<<nb64, 256, 0, stream>>>(P0, 128, s2a_Wl, s2a_Wr, s2a_bl, P1, N);
    agg_a_kernel<<<nbw, 256, 0, stream>>>(P1, off, csr, invc, P2, N);
    agg_b_kernel<<<nbw, 256, 0, stream>>>(P2, off, csr, invc, P0, N);
    gemm128_kernel<128, 2, 1, 1><<<nb64, 256, 0, stream>>>(P0, 128, s2b_Wl, s2b_Wr, s2b_bl, P1, N);

    // --- Head ---
    f3_kernel<<<(N + 7) / 8, 256, 0, stream>>>(P1, W_o1, b_o1, W_o2, b_o2, out, N);
}

// Round 2
// 1191.946 us; speedup vs baseline: 1.1041x; 1.1041x over previous
//
#include <hip/hip_runtime.h>
#include <hip/hip_bf16.h>

// ---------------------------------------------------------------------------
// BotGraphSAGE round 2: node-per-lane dense layers.
//  - Each thread owns ONE node and 32 output columns (VGPR accumulators).
//  - X tile staged TRANSPOSED in LDS ([k][node], stride 257): compute reads
//    are stride-1 conflict-free; W row loads are wave-uniform -> s_load
//    (scalar cache), FMA consumes the SGPR operand directly.
//  - f1a (des@W_des, K=768): split-K x4 across blocks + combine pass.
//  - 128-wide GEMMs: col-split x4 (32 cols per block).
//  - CSR build + 64-d aggregations unchanged (not yet shown hot).
// ---------------------------------------------------------------------------

__global__ void hist_kernel(const int* __restrict__ dst, int* __restrict__ cnt, int E) {
    int e = blockIdx.x * 256 + threadIdx.x;
    if (e < E) atomicAdd(&cnt[dst[e]], 1);
}

__global__ void scan_kernel(const int* __restrict__ cnt, int* __restrict__ off,
                            int* __restrict__ cursor, float* __restrict__ invc, int n) {
    __shared__ int sd[1024];
    __shared__ int carry;
    int tid = threadIdx.x;
    if (tid == 0) { carry = 0; off[0] = 0; }
    __syncthreads();
    for (int base = 0; base < n; base += 1024) {
        int v = (base + tid < n) ? cnt[base + tid] : 0;
        sd[tid] = v;
        __syncthreads();
        for (int d = 1; d < 1024; d <<= 1) {
            int t2 = (tid >= d) ? sd[tid - d] : 0;
            __syncthreads();
            sd[tid] += t2;
            __syncthreads();
        }
        if (base + tid < n) {
            int inc = carry + sd[tid];
            off[base + tid + 1] = inc;
            cursor[base + tid] = inc - v;
            invc[base + tid] = 1.0f / fmaxf((float)v, 1.0f);
        }
        __syncthreads();
        if (tid == 0) carry += sd[1023];
        __syncthreads();
    }
}

__global__ void scatter_kernel(const int* __restrict__ src, const int* __restrict__ dst,
                               int* __restrict__ cursor, int* __restrict__ csr, int E) {
    int e = blockIdx.x * 256 + threadIdx.x;
    if (e < E) {
        int d = dst[e];
        int p = atomicAdd(&cursor[d], 1);
        csr[p] = src[e];
    }
}

// ---------------------------------------------------------------------------
// f1a: des[N,768] @ W_des[768,32], split-K x4. Block = 256 nodes, one per
// thread. blockIdx.y selects K-range of 192. Partials -> part[y][node][32].
// ---------------------------------------------------------------------------
__global__ __launch_bounds__(256) void f1a_kernel(const float* __restrict__ des,
    const float* __restrict__ W, float* __restrict__ part, int n)
{
    __shared__ float sX[32 * 257];
    int t = threadIdx.x;
    int nbase = blockIdx.x * 256;
    int node = nbase + t;
    int kb0 = blockIdx.y * 192;
    float acc[32];
#pragma unroll
    for (int c = 0; c < 32; ++c) acc[c] = 0.f;

    for (int kc = 0; kc < 192; kc += 32) {
        __syncthreads();
#pragma unroll
        for (int r = 0; r < 8; ++r) {
            int i = r * 256 + t;
            int k4 = i & 7, nn = i >> 3;
            int gn = nbase + nn;
            float4 v = make_float4(0.f, 0.f, 0.f, 0.f);
            if (gn < n)
                v = *reinterpret_cast<const float4*>(des + (size_t)gn * 768 + kb0 + kc + k4 * 4);
            sX[(k4 * 4 + 0) * 257 + nn] = v.x;
            sX[(k4 * 4 + 1) * 257 + nn] = v.y;
            sX[(k4 * 4 + 2) * 257 + nn] = v.z;
            sX[(k4 * 4 + 3) * 257 + nn] = v.w;
        }
        __syncthreads();
        const float* wbase = W + (size_t)(kb0 + kc) * 32;
#pragma unroll 4
        for (int k = 0; k < 32; ++k) {
            float x = sX[k * 257 + t];
            const float* wr = wbase + k * 32;   // wave-uniform -> s_load
#pragma unroll
            for (int c = 0; c < 32; ++c) acc[c] = fmaf(x, wr[c], acc[c]);
        }
    }
    if (node < n) {
        float* po = part + ((size_t)blockIdx.y * n + node) * 32;
#pragma unroll
        for (int c4 = 0; c4 < 8; ++c4)
            *reinterpret_cast<float4*>(po + c4 * 4) =
                make_float4(acc[c4 * 4], acc[c4 * 4 + 1], acc[c4 * 4 + 2], acc[c4 * 4 + 3]);
    }
}

// combine 4 K-partials + bias -> leaky -> Xout[:,0:32] (stride 128)
__global__ void f1c_kernel(const float* __restrict__ part, const float* __restrict__ b,
                           float* __restrict__ Xout, int n) {
    int idx = blockIdx.x * 256 + threadIdx.x;
    if (idx >= n * 32) return;
    int node = idx >> 5, c = idx & 31;
    size_t stride = (size_t)n * 32;
    float v = part[idx] + part[stride + idx] + part[2 * stride + idx] + part[3 * stride + idx] + b[c];
    v = v > 0.f ? v : 0.01f * v;
    Xout[(size_t)node * 128 + c] = v;
}

// num/cat small linears -> leaky -> Xout[:,32:116]
__global__ __launch_bounds__(256) void f1b_kernel(const float* __restrict__ nump,
    const float* __restrict__ catp,
    const float* __restrict__ Wn, const float* __restrict__ bn,
    const float* __restrict__ Wc, const float* __restrict__ bc,
    float* __restrict__ Xout, int n)
{
    int idx = blockIdx.x * 256 + threadIdx.x;
    if (idx >= n * 84) return;
    int node = idx / 84;
    int c = idx - node * 84;
    float v;
    if (c < 42) {
        v = bn[c];
#pragma unroll
        for (int k = 0; k < 4; ++k) v += nump[node * 4 + k] * Wn[k * 42 + c];
    } else {
        int o = c - 42;
        v = bc[o];
#pragma unroll
        for (int k = 0; k < 3; ++k) v += catp[node * 3 + k] * Wc[k * 42 + o];
    }
    v = v > 0.f ? v : 0.01f * v;
    Xout[(size_t)node * 128 + 32 + c] = v;
}

// ---------------------------------------------------------------------------
// Node-per-lane GEMM: X[N,128-stride] @ W[K,128] -> Y[N,128-stride].
// Block = 256 nodes; blockIdx.y = cs in 0..3 selects 32 output cols.
// MODE 0: W = WA[K][128]
// MODE 1: cols 0:64 from WA[K][64], cols 64:128 from WB[K][64]
// MODE 2: rows 0:64 from WA[64][128], rows 64:128 from WB[64][128]
// BIASM 0: none; 1: bias[128]; 2: bias[64] on cols >= 64
// ACT 0: none; 1: relu; 2: leaky
// ---------------------------------------------------------------------------
template<int K, int MODE, int ACT, int BIASM>
__global__ __launch_bounds__(256) void gemm_np_kernel(
    const float* __restrict__ X,
    const float* __restrict__ WA, const float* __restrict__ WB,
    const float* __restrict__ bias,
    float* __restrict__ Y, int n)
{
    __shared__ float sX[32 * 257];
    int t = threadIdx.x;
    int nbase = blockIdx.x * 256;
    int node = nbase + t;
    int cs = blockIdx.y;           // 0..3
    float acc[32];
#pragma unroll
    for (int c = 0; c < 32; ++c) acc[c] = 0.f;

#pragma unroll
    for (int kb = 0; kb < K; kb += 32) {
        const int klim = (K - kb < 32) ? (K - kb) : 32;
        __syncthreads();
#pragma unroll
        for (int r = 0; r < 8; ++r) {
            int i = r * 256 + t;
            int k4 = i & 7, nn = i >> 3;
            if (k4 * 4 < klim) {
                int gn = nbase + nn;
                float4 v = make_float4(0.f, 0.f, 0.f, 0.f);
                if (gn < n)
                    v = *reinterpret_cast<const float4*>(X + (size_t)gn * 128 + kb + k4 * 4);
                sX[(k4 * 4 + 0) * 257 + nn] = v.x;
                sX[(k4 * 4 + 1) * 257 + nn] = v.y;
                sX[(k4 * 4 + 2) * 257 + nn] = v.z;
                sX[(k4 * 4 + 3) * 257 + nn] = v.w;
            }
        }
        __syncthreads();
#pragma unroll 4
        for (int k = 0; k < klim; ++k) {
            float x = sX[k * 257 + t];
            const float* wr;   // wave-uniform -> s_load
            int kk = kb + k;
            if (MODE == 0)      wr = WA + (size_t)kk * 128 + cs * 32;
            else if (MODE == 1) wr = (cs < 2) ? (WA + (size_t)kk * 64 + cs * 32)
                                              : (WB + (size_t)kk * 64 + (cs - 2) * 32);
            else                wr = (kk < 64) ? (WA + (size_t)kk * 128 + cs * 32)
                                               : (WB + (size_t)(kk - 64) * 128 + cs * 32);
#pragma unroll
            for (int c = 0; c < 32; ++c) acc[c] = fmaf(x, wr[c], acc[c]);
        }
    }

    if (node < n) {
        int c0 = cs * 32;
        float* yp = Y + (size_t)node * 128 + c0;
#pragma unroll
        for (int c = 0; c < 32; ++c) {
            float v = acc[c];
            if (BIASM == 1) v += bias[c0 + c];
            if (BIASM == 2) { if (cs >= 2) v += bias[c0 - 64 + c]; }
            if (ACT == 1) v = fmaxf(v, 0.f);
            else if (ACT == 2) v = v > 0.f ? v : 0.01f * v;
            acc[c] = v;
        }
#pragma unroll
        for (int c4 = 0; c4 < 8; ++c4)
            *reinterpret_cast<float4*>(yp + c4 * 4) =
                make_float4(acc[c4 * 4], acc[c4 * 4 + 1], acc[c4 * 4 + 2], acc[c4 * 4 + 3]);
    }
}

// SAGE layer-a epilogue: H[dst] = relu(mean_agg(Y[:,0:64]) + Y[dst,64:128])
__global__ __launch_bounds__(256) void agg_a_kernel(const float* __restrict__ Y,
    const int* __restrict__ off, const int* __restrict__ csr,
    const float* __restrict__ invc, float* __restrict__ H, int n)
{
    int wid = (blockIdx.x * 256 + threadIdx.x) >> 6;
    int f = threadIdx.x & 63;
    if (wid >= n) return;
    int b = off[wid], e = off[wid + 1];
    float acc = 0.f;
    for (; b + 4 <= e; b += 4) {
        int s0 = csr[b], s1 = csr[b + 1], s2 = csr[b + 2], s3 = csr[b + 3];
        float v0 = Y[(size_t)s0 * 128 + f];
        float v1 = Y[(size_t)s1 * 128 + f];
        float v2 = Y[(size_t)s2 * 128 + f];
        float v3 = Y[(size_t)s3 * 128 + f];
        acc += v0 + v1 + v2 + v3;
    }
    for (; b < e; ++b) acc += Y[(size_t)csr[b] * 128 + f];
    float v = acc * invc[wid] + Y[(size_t)wid * 128 + 64 + f];
    H[(size_t)wid * 64 + f] = fmaxf(v, 0.f);
}

// SAGE layer-b pre-GEMM: Z[dst,0:64] = mean_agg(H), Z[dst,64:128] = H[dst]
__global__ __launch_bounds__(256) void agg_b_kernel(const float* __restrict__ H,
    const int* __restrict__ off, const int* __restrict__ csr,
    const float* __restrict__ invc, float* __restrict__ Z, int n)
{
    int wid = (blockIdx.x * 256 + threadIdx.x) >> 6;
    int f = threadIdx.x & 63;
    if (wid >= n) return;
    int b = off[wid], e = off[wid + 1];
    float acc = 0.f;
    for (; b + 4 <= e; b += 4) {
        int s0 = csr[b], s1 = csr[b + 1], s2 = csr[b + 2], s3 = csr[b + 3];
        acc += H[(size_t)s0 * 64 + f] + H[(size_t)s1 * 64 + f]
             + H[(size_t)s2 * 64 + f] + H[(size_t)s3 * 64 + f];
    }
    for (; b < e; ++b) acc += H[(size_t)csr[b] * 64 + f];
    Z[(size_t)wid * 128 + f] = acc * invc[wid];
    Z[(size_t)wid * 128 + 64 + f] = H[(size_t)wid * 64 + f];
}

// Head stage 2: out[node] = H[node,0:128] . W2[128,2] + b2; one wave per node.
__global__ __launch_bounds__(256) void head2_kernel(const float* __restrict__ H,
    const float* __restrict__ W2, const float* __restrict__ b2,
    float* __restrict__ out, int n)
{
    int l = threadIdx.x & 63;
    int node = (blockIdx.x * 256 + threadIdx.x) >> 6;
    if (node >= n) return;
    float x0 = H[(size_t)node * 128 + l];
    float x1 = H[(size_t)node * 128 + 64 + l];
    float a0 = x0 * W2[l * 2]     + x1 * W2[(64 + l) * 2];
    float a1 = x0 * W2[l * 2 + 1] + x1 * W2[(64 + l) * 2 + 1];
#pragma unroll
    for (int s = 32; s > 0; s >>= 1) {
        a0 += __shfl_down(a0, s, 64);
        a1 += __shfl_down(a1, s, 64);
    }
    if (l == 0) {
        out[(size_t)node * 2]     = a0 + b2[0];
        out[(size_t)node * 2 + 1] = a1 + b2[1];
    }
}

extern "C" void kernel_launch(void* const* d_in, const int* in_sizes, int n_in,
                              void* d_out, int out_size, void* d_ws, size_t ws_size,
                              hipStream_t stream)
{
    const float* des   = (const float*)d_in[0];
    const float* nump  = (const float*)d_in[2];
    const float* catp  = (const float*)d_in[3];
    const int*   ei    = (const int*)d_in[4];
    const float* W_des = (const float*)d_in[5];  const float* b_des = (const float*)d_in[6];
    const float* W_num = (const float*)d_in[7];  const float* b_num = (const float*)d_in[8];
    const float* W_cat = (const float*)d_in[9];  const float* b_cat = (const float*)d_in[10];
    const float* W_in  = (const float*)d_in[11]; const float* b_in  = (const float*)d_in[12];
    const float* s1a_Wl = (const float*)d_in[13]; const float* s1a_bl = (const float*)d_in[14];
    const float* s1a_Wr = (const float*)d_in[15];
    const float* s1b_Wl = (const float*)d_in[16]; const float* s1b_bl = (const float*)d_in[17];
    const float* s1b_Wr = (const float*)d_in[18];
    const float* s2a_Wl = (const float*)d_in[19]; const float* s2a_bl = (const float*)d_in[20];
    const float* s2a_Wr = (const float*)d_in[21];
    const float* s2b_Wl = (const float*)d_in[22]; const float* s2b_bl = (const float*)d_in[23];
    const float* s2b_Wr = (const float*)d_in[24];
    const float* W_o1  = (const float*)d_in[25]; const float* b_o1 = (const float*)d_in[26];
    const float* W_o2  = (const float*)d_in[27]; const float* b_o2 = (const float*)d_in[28];
    float* out = (float*)d_out;

    int N = in_sizes[0] / 768;
    int E = in_sizes[4] / 2;
    const int* srcp = ei;
    const int* dstp = ei + E;

    float* P0 = (float*)d_ws;
    float* P1 = P0 + (size_t)128 * N;
    float* P2 = P1 + (size_t)128 * N;   // doubles as f1a partial buffer (4*N*32 = 128*N)
    int* cnt = (int*)(P2 + (size_t)128 * N);
    int* off = cnt + N;
    int* cursor = off + (N + 1);
    float* invc = (float*)(cursor + N);
    int* csr = (int*)(invc + N);

    // --- CSR build ---
    hipMemsetAsync(cnt, 0, (size_t)N * sizeof(int), stream);
    int eb = (E + 255) / 256;
    hist_kernel<<<eb, 256, 0, stream>>>(dstp, cnt, E);
    scan_kernel<<<1, 1024, 0, stream>>>(cnt, off, cursor, invc, N);
    scatter_kernel<<<eb, 256, 0, stream>>>(srcp, dstp, cursor, csr, E);

    int nbn = (N + 255) / 256;          // node blocks (256 nodes each)
    dim3 gemm_grid(nbn, 4);
    int nbw = (N + 3) / 4;              // wave-per-node blocks

    // --- Front MLP ---
    f1a_kernel<<<dim3(nbn, 4), 256, 0, stream>>>(des, W_des, P2, N);
    f1b_kernel<<<(N * 84 + 255) / 256, 256, 0, stream>>>(nump, catp, W_num, b_num, W_cat, b_cat, P0, N);
    f1c_kernel<<<(N * 32 + 255) / 256, 256, 0, stream>>>(P2, b_des, P0, N);
    gemm_np_kernel<116, 0, 2, 1><<<gemm_grid, 256, 0, stream>>>(P0, W_in, nullptr, b_in, P1, N);

    // --- SAGE block 1 ---
    gemm_np_kernel<128, 1, 0, 2><<<gemm_grid, 256, 0, stream>>>(P1, s1a_Wl, s1a_Wr, s1a_bl, P0, N);
    agg_a_kernel<<<nbw, 256, 0, stream>>>(P0, off, csr, invc, P2, N);
    agg_b_kernel<<<nbw, 256, 0, stream>>>(P2, off, csr, invc, P1, N);
    gemm_np_kernel<128, 2, 1, 1><<<gemm_grid, 256, 0, stream>>>(P1, s1b_Wl, s1b_Wr, s1b_bl, P0, N);

    // --- SAGE block 2 ---
    gemm_np_kernel<128, 1, 0, 2><<<gemm_grid, 256, 0, stream>>>(P0, s2a_Wl, s2a_Wr, s2a_bl, P1, N);
    agg_a_kernel<<<nbw, 256, 0, stream>>>(P1, off, csr, invc, P2, N);
    agg_b_kernel<<<nbw, 256, 0, stream>>>(P2, off, csr, invc, P0, N);
    gemm_np_kernel<128, 2, 1, 1><<<gemm_grid, 256, 0, stream>>>(P0, s2b_Wl, s2b_Wr, s2b_bl, P1, N);

    // --- Head ---
    gemm_np_kernel<128, 0, 2, 1><<<gemm_grid, 256, 0, stream>>>(P1, W_o1, nullptr, b_o1, P2, N);
    head2_kernel<<<(N + 3) / 4, 256, 0, stream>>>(P2, W_o2, b_o2, out, N);
}

// Round 3
// 999.053 us; speedup vs baseline: 1.3172x; 1.1931x over previous
//
#include <hip/hip_runtime.h>
#include <hip/hip_bf16.h>

// ---------------------------------------------------------------------------
// BotGraphSAGE round 3:
//  - CSR build rework: multi-block scan (3 small kernels) + bucketed
//    two-phase scatter (LDS histogram binning -> per-bucket LDS-cursor sort)
//    to kill the 16x write amplification of the naive scatter.
//  - Aggregations: 8-deep gather unrolling for more memory-level parallelism.
//  - Dense layers unchanged (node-per-lane, SGPR weight broadcast).
// ---------------------------------------------------------------------------

#define BK_SHIFT 8
#define BK_SIZE 256

__global__ void hist_kernel(const int* __restrict__ dst, int* __restrict__ cnt, int E) {
    int e = blockIdx.x * 256 + threadIdx.x;
    if (e < E) atomicAdd(&cnt[dst[e]], 1);
}

// ---- multi-block exclusive scan over cnt[N] -> off[N+1], invc[N] ----
__global__ void scan_reduce_kernel(const int* __restrict__ cnt, int* __restrict__ bsum, int n) {
    int t = threadIdx.x;
    int i = blockIdx.x * 256 + t;
    int v = (i < n) ? cnt[i] : 0;
#pragma unroll
    for (int s = 32; s > 0; s >>= 1) v += __shfl_down(v, s, 64);
    __shared__ int ws[4];
    if ((t & 63) == 0) ws[t >> 6] = v;
    __syncthreads();
    if (t == 0) bsum[blockIdx.x] = ws[0] + ws[1] + ws[2] + ws[3];
}

__global__ void scan_mid_kernel(const int* __restrict__ bsum, int* __restrict__ bbase, int nb) {
    __shared__ int sd[256];
    __shared__ int carry;
    int t = threadIdx.x;
    if (t == 0) carry = 0;
    __syncthreads();
    for (int base = 0; base < nb; base += 256) {
        int v = (base + t < nb) ? bsum[base + t] : 0;
        sd[t] = v;
        __syncthreads();
        for (int d = 1; d < 256; d <<= 1) {
            int x = (t >= d) ? sd[t - d] : 0;
            __syncthreads();
            sd[t] += x;
            __syncthreads();
        }
        if (base + t < nb) bbase[base + t] = carry + sd[t] - v;
        __syncthreads();
        if (t == 0) carry += sd[255];
        __syncthreads();
    }
}

__global__ void scan_final_kernel(const int* __restrict__ cnt, const int* __restrict__ bbase,
                                  int* __restrict__ off, float* __restrict__ invc, int n) {
    __shared__ int sd[256];
    int t = threadIdx.x;
    int i = blockIdx.x * 256 + t;
    int v = (i < n) ? cnt[i] : 0;
    sd[t] = v;
    __syncthreads();
    for (int d = 1; d < 256; d <<= 1) {
        int x = (t >= d) ? sd[t - d] : 0;
        __syncthreads();
        sd[t] += x;
        __syncthreads();
    }
    if (i < n) {
        off[i + 1] = bbase[blockIdx.x] + sd[t];
        invc[i] = 1.0f / fmaxf((float)v, 1.0f);
    }
    if (i == 0) off[0] = 0;
}

__global__ void init_gcur_kernel(const int* __restrict__ off, int* __restrict__ gcur, int nb, int n) {
    int b = blockIdx.x * 256 + threadIdx.x;
    if (b < nb) gcur[b] = off[b * BK_SIZE];
}

// ---- phase A: bin edges into buckets of BK_SIZE dst nodes ----
__global__ __launch_bounds__(256) void bucketA_kernel(const int* __restrict__ src,
    const int* __restrict__ dst, int* __restrict__ gcur,
    uint2* __restrict__ pairs, int E, int nb)
{
    __shared__ int lcnt[256];
    __shared__ int lbase[256];
    int t = threadIdx.x;
    int cbase = blockIdx.x * 4096;
    lcnt[t] = 0;
    __syncthreads();
#pragma unroll
    for (int r = 0; r < 16; ++r) {
        int e = cbase + r * 256 + t;
        if (e < E) atomicAdd(&lcnt[dst[e] >> BK_SHIFT], 1);
    }
    __syncthreads();
    if (t < nb && lcnt[t] > 0) lbase[t] = atomicAdd(&gcur[t], lcnt[t]);
    lcnt[t] = 0;
    __syncthreads();
#pragma unroll
    for (int r = 0; r < 16; ++r) {
        int e = cbase + r * 256 + t;
        if (e < E) {
            int d = dst[e];
            int bk = d >> BK_SHIFT;
            int pos = lbase[bk] + atomicAdd(&lcnt[bk], 1);
            pairs[pos] = make_uint2((unsigned)src[e], (unsigned)d);
        }
    }
}

// ---- phase B: per-bucket LDS-cursor final placement ----
__global__ __launch_bounds__(256) void bucketB_kernel(const uint2* __restrict__ pairs,
    const int* __restrict__ off, int* __restrict__ csr, int n)
{
    __shared__ int lcur[BK_SIZE];
    int t = threadIdx.x;
    int b = blockIdx.x;
    int d0 = b * BK_SIZE;
    int dlim = min(BK_SIZE, n - d0);
    if (t < dlim) lcur[t] = off[d0 + t];
    __syncthreads();
    int start = off[d0];
    int end = off[min(d0 + BK_SIZE, n)];
    for (int i = start + t; i < end; i += 256) {
        uint2 p = pairs[i];
        int pos = atomicAdd(&lcur[p.y & (BK_SIZE - 1)], 1);
        csr[pos] = (int)p.x;
    }
}

// ---------------------------------------------------------------------------
// f1a: des[N,768] @ W_des[768,32], split-K x4, node-per-lane.
// ---------------------------------------------------------------------------
__global__ __launch_bounds__(256) void f1a_kernel(const float* __restrict__ des,
    const float* __restrict__ W, float* __restrict__ part, int n)
{
    __shared__ float sX[32 * 257];
    int t = threadIdx.x;
    int nbase = blockIdx.x * 256;
    int node = nbase + t;
    int kb0 = blockIdx.y * 192;
    float acc[32];
#pragma unroll
    for (int c = 0; c < 32; ++c) acc[c] = 0.f;

    for (int kc = 0; kc < 192; kc += 32) {
        __syncthreads();
#pragma unroll
        for (int r = 0; r < 8; ++r) {
            int i = r * 256 + t;
            int k4 = i & 7, nn = i >> 3;
            int gn = nbase + nn;
            float4 v = make_float4(0.f, 0.f, 0.f, 0.f);
            if (gn < n)
                v = *reinterpret_cast<const float4*>(des + (size_t)gn * 768 + kb0 + kc + k4 * 4);
            sX[(k4 * 4 + 0) * 257 + nn] = v.x;
            sX[(k4 * 4 + 1) * 257 + nn] = v.y;
            sX[(k4 * 4 + 2) * 257 + nn] = v.z;
            sX[(k4 * 4 + 3) * 257 + nn] = v.w;
        }
        __syncthreads();
        const float* wbase = W + (size_t)(kb0 + kc) * 32;
#pragma unroll 4
        for (int k = 0; k < 32; ++k) {
            float x = sX[k * 257 + t];
            const float* wr = wbase + k * 32;   // wave-uniform -> s_load
#pragma unroll
            for (int c = 0; c < 32; ++c) acc[c] = fmaf(x, wr[c], acc[c]);
        }
    }
    if (node < n) {
        float* po = part + ((size_t)blockIdx.y * n + node) * 32;
#pragma unroll
        for (int c4 = 0; c4 < 8; ++c4)
            *reinterpret_cast<float4*>(po + c4 * 4) =
                make_float4(acc[c4 * 4], acc[c4 * 4 + 1], acc[c4 * 4 + 2], acc[c4 * 4 + 3]);
    }
}

__global__ void f1c_kernel(const float* __restrict__ part, const float* __restrict__ b,
                           float* __restrict__ Xout, int n) {
    int idx = blockIdx.x * 256 + threadIdx.x;
    if (idx >= n * 32) return;
    int node = idx >> 5, c = idx & 31;
    size_t stride = (size_t)n * 32;
    float v = part[idx] + part[stride + idx] + part[2 * stride + idx] + part[3 * stride + idx] + b[c];
    v = v > 0.f ? v : 0.01f * v;
    Xout[(size_t)node * 128 + c] = v;
}

__global__ __launch_bounds__(256) void f1b_kernel(const float* __restrict__ nump,
    const float* __restrict__ catp,
    const float* __restrict__ Wn, const float* __restrict__ bn,
    const float* __restrict__ Wc, const float* __restrict__ bc,
    float* __restrict__ Xout, int n)
{
    int idx = blockIdx.x * 256 + threadIdx.x;
    if (idx >= n * 84) return;
    int node = idx / 84;
    int c = idx - node * 84;
    float v;
    if (c < 42) {
        v = bn[c];
#pragma unroll
        for (int k = 0; k < 4; ++k) v += nump[node * 4 + k] * Wn[k * 42 + c];
    } else {
        int o = c - 42;
        v = bc[o];
#pragma unroll
        for (int k = 0; k < 3; ++k) v += catp[node * 3 + k] * Wc[k * 42 + o];
    }
    v = v > 0.f ? v : 0.01f * v;
    Xout[(size_t)node * 128 + 32 + c] = v;
}

// ---------------------------------------------------------------------------
// Node-per-lane GEMM (see round-2 notes).
// ---------------------------------------------------------------------------
template<int K, int MODE, int ACT, int BIASM>
__global__ __launch_bounds__(256) void gemm_np_kernel(
    const float* __restrict__ X,
    const float* __restrict__ WA, const float* __restrict__ WB,
    const float* __restrict__ bias,
    float* __restrict__ Y, int n)
{
    __shared__ float sX[32 * 257];
    int t = threadIdx.x;
    int nbase = blockIdx.x * 256;
    int node = nbase + t;
    int cs = blockIdx.y;
    float acc[32];
#pragma unroll
    for (int c = 0; c < 32; ++c) acc[c] = 0.f;

#pragma unroll
    for (int kb = 0; kb < K; kb += 32) {
        const int klim = (K - kb < 32) ? (K - kb) : 32;
        __syncthreads();
#pragma unroll
        for (int r = 0; r < 8; ++r) {
            int i = r * 256 + t;
            int k4 = i & 7, nn = i >> 3;
            if (k4 * 4 < klim) {
                int gn = nbase + nn;
                float4 v = make_float4(0.f, 0.f, 0.f, 0.f);
                if (gn < n)
                    v = *reinterpret_cast<const float4*>(X + (size_t)gn * 128 + kb + k4 * 4);
                sX[(k4 * 4 + 0) * 257 + nn] = v.x;
                sX[(k4 * 4 + 1) * 257 + nn] = v.y;
                sX[(k4 * 4 + 2) * 257 + nn] = v.z;
                sX[(k4 * 4 + 3) * 257 + nn] = v.w;
            }
        }
        __syncthreads();
#pragma unroll 4
        for (int k = 0; k < klim; ++k) {
            float x = sX[k * 257 + t];
            const float* wr;
            int kk = kb + k;
            if (MODE == 0)      wr = WA + (size_t)kk * 128 + cs * 32;
            else if (MODE == 1) wr = (cs < 2) ? (WA + (size_t)kk * 64 + cs * 32)
                                              : (WB + (size_t)kk * 64 + (cs - 2) * 32);
            else                wr = (kk < 64) ? (WA + (size_t)kk * 128 + cs * 32)
                                               : (WB + (size_t)(kk - 64) * 128 + cs * 32);
#pragma unroll
            for (int c = 0; c < 32; ++c) acc[c] = fmaf(x, wr[c], acc[c]);
        }
    }

    if (node < n) {
        int c0 = cs * 32;
        float* yp = Y + (size_t)node * 128 + c0;
#pragma unroll
        for (int c = 0; c < 32; ++c) {
            float v = acc[c];
            if (BIASM == 1) v += bias[c0 + c];
            if (BIASM == 2) { if (cs >= 2) v += bias[c0 - 64 + c]; }
            if (ACT == 1) v = fmaxf(v, 0.f);
            else if (ACT == 2) v = v > 0.f ? v : 0.01f * v;
            acc[c] = v;
        }
#pragma unroll
        for (int c4 = 0; c4 < 8; ++c4)
            *reinterpret_cast<float4*>(yp + c4 * 4) =
                make_float4(acc[c4 * 4], acc[c4 * 4 + 1], acc[c4 * 4 + 2], acc[c4 * 4 + 3]);
    }
}

// SAGE layer-a epilogue: H[dst] = relu(mean_agg(Y[:,0:64]) + Y[dst,64:128])
__global__ __launch_bounds__(256) void agg_a_kernel(const float* __restrict__ Y,
    const int* __restrict__ off, const int* __restrict__ csr,
    const float* __restrict__ invc, float* __restrict__ H, int n)
{
    int wid = (blockIdx.x * 256 + threadIdx.x) >> 6;
    int f = threadIdx.x & 63;
    if (wid >= n) return;
    float root = Y[(size_t)wid * 128 + 64 + f];
    int b = off[wid], e = off[wid + 1];
    float acc = 0.f;
    for (; b + 8 <= e; b += 8) {
        int idx[8];
#pragma unroll
        for (int j = 0; j < 8; ++j) idx[j] = csr[b + j];
        float v[8];
#pragma unroll
        for (int j = 0; j < 8; ++j) v[j] = Y[(size_t)idx[j] * 128 + f];
#pragma unroll
        for (int j = 0; j < 8; ++j) acc += v[j];
    }
    for (; b + 2 <= e; b += 2) {
        int s0 = csr[b], s1 = csr[b + 1];
        acc += Y[(size_t)s0 * 128 + f] + Y[(size_t)s1 * 128 + f];
    }
    for (; b < e; ++b) acc += Y[(size_t)csr[b] * 128 + f];
    float v = acc * invc[wid] + root;
    H[(size_t)wid * 64 + f] = fmaxf(v, 0.f);
}

// SAGE layer-b pre-GEMM: Z[dst,0:64] = mean_agg(H), Z[dst,64:128] = H[dst]
__global__ __launch_bounds__(256) void agg_b_kernel(const float* __restrict__ H,
    const int* __restrict__ off, const int* __restrict__ csr,
    const float* __restrict__ invc, float* __restrict__ Z, int n)
{
    int wid = (blockIdx.x * 256 + threadIdx.x) >> 6;
    int f = threadIdx.x & 63;
    if (wid >= n) return;
    float root = H[(size_t)wid * 64 + f];
    int b = off[wid], e = off[wid + 1];
    float acc = 0.f;
    for (; b + 8 <= e; b += 8) {
        int idx[8];
#pragma unroll
        for (int j = 0; j < 8; ++j) idx[j] = csr[b + j];
        float v[8];
#pragma unroll
        for (int j = 0; j < 8; ++j) v[j] = H[(size_t)idx[j] * 64 + f];
#pragma unroll
        for (int j = 0; j < 8; ++j) acc += v[j];
    }
    for (; b + 2 <= e; b += 2) {
        int s0 = csr[b], s1 = csr[b + 1];
        acc += H[(size_t)s0 * 64 + f] + H[(size_t)s1 * 64 + f];
    }
    for (; b < e; ++b) acc += H[(size_t)csr[b] * 64 + f];
    Z[(size_t)wid * 128 + f] = acc * invc[wid];
    Z[(size_t)wid * 128 + 64 + f] = root;
}

// Head stage 2: out[node] = H[node,0:128] . W2[128,2] + b2; one wave per node.
__global__ __launch_bounds__(256) void head2_kernel(const float* __restrict__ H,
    const float* __restrict__ W2, const float* __restrict__ b2,
    float* __restrict__ out, int n)
{
    int l = threadIdx.x & 63;
    int node = (blockIdx.x * 256 + threadIdx.x) >> 6;
    if (node >= n) return;
    float x0 = H[(size_t)node * 128 + l];
    float x1 = H[(size_t)node * 128 + 64 + l];
    float a0 = x0 * W2[l * 2]     + x1 * W2[(64 + l) * 2];
    float a1 = x0 * W2[l * 2 + 1] + x1 * W2[(64 + l) * 2 + 1];
#pragma unroll
    for (int s = 32; s > 0; s >>= 1) {
        a0 += __shfl_down(a0, s, 64);
        a1 += __shfl_down(a1, s, 64);
    }
    if (l == 0) {
        out[(size_t)node * 2]     = a0 + b2[0];
        out[(size_t)node * 2 + 1] = a1 + b2[1];
    }
}

extern "C" void kernel_launch(void* const* d_in, const int* in_sizes, int n_in,
                              void* d_out, int out_size, void* d_ws, size_t ws_size,
                              hipStream_t stream)
{
    const float* des   = (const float*)d_in[0];
    const float* nump  = (const float*)d_in[2];
    const float* catp  = (const float*)d_in[3];
    const int*   ei    = (const int*)d_in[4];
    const float* W_des = (const float*)d_in[5];  const float* b_des = (const float*)d_in[6];
    const float* W_num = (const float*)d_in[7];  const float* b_num = (const float*)d_in[8];
    const float* W_cat = (const float*)d_in[9];  const float* b_cat = (const float*)d_in[10];
    const float* W_in  = (const float*)d_in[11]; const float* b_in  = (const float*)d_in[12];
    const float* s1a_Wl = (const float*)d_in[13]; const float* s1a_bl = (const float*)d_in[14];
    const float* s1a_Wr = (const float*)d_in[15];
    const float* s1b_Wl = (const float*)d_in[16]; const float* s1b_bl = (const float*)d_in[17];
    const float* s1b_Wr = (const float*)d_in[18];
    const float* s2a_Wl = (const float*)d_in[19]; const float* s2a_bl = (const float*)d_in[20];
    const float* s2a_Wr = (const float*)d_in[21];
    const float* s2b_Wl = (const float*)d_in[22]; const float* s2b_bl = (const float*)d_in[23];
    const float* s2b_Wr = (const float*)d_in[24];
    const float* W_o1  = (const float*)d_in[25]; const float* b_o1 = (const float*)d_in[26];
    const float* W_o2  = (const float*)d_in[27]; const float* b_o2 = (const float*)d_in[28];
    float* out = (float*)d_out;

    int N = in_sizes[0] / 768;
    int E = in_sizes[4] / 2;
    const int* srcp = ei;
    const int* dstp = ei + E;
    int NB = (N + BK_SIZE - 1) >> BK_SHIFT;       // dst buckets
    int NBLK = (N + 255) / 256;                   // scan blocks

    float* P0 = (float*)d_ws;
    float* P1 = P0 + (size_t)128 * N;
    float* P2 = P1 + (size_t)128 * N;   // f1a partials / agg temp / pair buffer (E*8B <= 128N*4B)
    int* cnt   = (int*)(P2 + (size_t)128 * N);
    int* off   = cnt + N;
    float* invc = (float*)(off + (N + 1));
    int* csr   = (int*)(invc + N);
    int* bsum  = csr + E;
    int* bbase = bsum + NBLK;
    int* gcur  = bbase + NBLK;
    uint2* pairs = (uint2*)P2;

    // --- CSR build ---
    hipMemsetAsync(cnt, 0, (size_t)N * sizeof(int), stream);
    hist_kernel<<<(E + 255) / 256, 256, 0, stream>>>(dstp, cnt, E);
    scan_reduce_kernel<<<NBLK, 256, 0, stream>>>(cnt, bsum, N);
    scan_mid_kernel<<<1, 256, 0, stream>>>(bsum, bbase, NBLK);
    scan_final_kernel<<<NBLK, 256, 0, stream>>>(cnt, bbase, off, invc, N);
    init_gcur_kernel<<<(NB + 255) / 256, 256, 0, stream>>>(off, gcur, NB, N);
    bucketA_kernel<<<(E + 4095) / 4096, 256, 0, stream>>>(srcp, dstp, gcur, pairs, E, NB);
    bucketB_kernel<<<NB, 256, 0, stream>>>(pairs, off, csr, N);

    int nbn = (N + 255) / 256;
    dim3 gemm_grid(nbn, 4);
    int nbw = (N + 3) / 4;

    // --- Front MLP ---
    f1a_kernel<<<dim3(nbn, 4), 256, 0, stream>>>(des, W_des, P2, N);
    f1b_kernel<<<(N * 84 + 255) / 256, 256, 0, stream>>>(nump, catp, W_num, b_num, W_cat, b_cat, P0, N);
    f1c_kernel<<<(N * 32 + 255) / 256, 256, 0, stream>>>(P2, b_des, P0, N);
    gemm_np_kernel<116, 0, 2, 1><<<gemm_grid, 256, 0, stream>>>(P0, W_in, nullptr, b_in, P1, N);

    // --- SAGE block 1 ---
    gemm_np_kernel<128, 1, 0, 2><<<gemm_grid, 256, 0, stream>>>(P1, s1a_Wl, s1a_Wr, s1a_bl, P0, N);
    agg_a_kernel<<<nbw, 256, 0, stream>>>(P0, off, csr, invc, P2, N);
    agg_b_kernel<<<nbw, 256, 0, stream>>>(P2, off, csr, invc, P1, N);
    gemm_np_kernel<128, 2, 1, 1><<<gemm_grid, 256, 0, stream>>>(P1, s1b_Wl, s1b_Wr, s1b_bl, P0, N);

    // --- SAGE block 2 ---
    gemm_np_kernel<128, 1, 0, 2><<<gemm_grid, 256, 0, stream>>>(P0, s2a_Wl, s2a_Wr, s2a_bl, P1, N);
    agg_a_kernel<<<nbw, 256, 0, stream>>>(P1, off, csr, invc, P2, N);
    agg_b_kernel<<<nbw, 256, 0, stream>>>(P2, off, csr, invc, P0, N);
    gemm_np_kernel<128, 2, 1, 1><<<gemm_grid, 256, 0, stream>>>(P0, s2b_Wl, s2b_Wr, s2b_bl, P1, N);

    // --- Head ---
    gemm_np_kernel<128, 0, 2, 1><<<gemm_grid, 256, 0, stream>>>(P1, W_o1, nullptr, b_o1, P2, N);
    head2_kernel<<<(N + 3) / 4, 256, 0, stream>>>(P2, W_o2, b_o2, out, N);
}